// Round 7
// baseline (16529.016 us; speedup 1.0000x reference)
//
#include <hip/hip_runtime.h>
#include <hip/hip_fp16.h>
#include <math.h>

#define B_ 64
#define T_ 512
#define FSTR 8   // flag stride in ints (32 B) — limits same-cacheline flag contention

// ---------------------------------------------------------------------------
// GEMM: C[M,N] = (A[M,K] * mask[row/T_, :]) @ W[K,N] + bias[N]
// fp32, 64x64 tile, TK=32, 256 threads, 4x4 microtile per thread.
// ---------------------------------------------------------------------------
__global__ __launch_bounds__(256) void gemm_mask_kernel(
    const float* __restrict__ A, const float* __restrict__ W,
    const float* __restrict__ bias, const float* __restrict__ mask,
    float* __restrict__ C, int M, int N, int K)
{
    const int TM = 64, TN = 64, TK = 32;
    __shared__ __align__(16) float As[TK][68];
    __shared__ __align__(16) float Bs[TK][68];

    const int tid = threadIdx.x;
    const int bn = blockIdx.x;
    const int bm = blockIdx.y;
    const int row0 = bm * TM;
    const int b = row0 / T_;

    const int ty = tid >> 4;
    const int tx = tid & 15;
    const int m0 = ty * 4;
    const int n0 = tx * 4;

    float acc[4][4];
#pragma unroll
    for (int i = 0; i < 4; i++)
#pragma unroll
        for (int j = 0; j < 4; j++) acc[i][j] = 0.f;

    for (int kk = 0; kk < K; kk += TK) {
        {
            const int r = tid >> 3;
            const int kq = (tid & 7) << 2;
            const float4 mv = *(const float4*)(mask + (size_t)b * K + kk + kq);
#pragma unroll
            for (int rr = 0; rr < 2; rr++) {
                const int r2 = r + rr * 32;
                const float4 av = *(const float4*)(A + (size_t)(row0 + r2) * K + kk + kq);
                As[kq + 0][r2] = av.x * mv.x;
                As[kq + 1][r2] = av.y * mv.y;
                As[kq + 2][r2] = av.z * mv.z;
                As[kq + 3][r2] = av.w * mv.w;
            }
        }
        {
            const int kr = tid >> 4;
            const int nq = (tid & 15) << 2;
#pragma unroll
            for (int rr = 0; rr < 2; rr++) {
                const int k2 = kr + rr * 16;
                const float4 bv = *(const float4*)(W + (size_t)(kk + k2) * N + bn * TN + nq);
                *(float4*)&Bs[k2][nq] = bv;
            }
        }
        __syncthreads();

#pragma unroll
        for (int k = 0; k < TK; k++) {
            const float4 av = *(const float4*)&As[k][m0];
            const float4 bv = *(const float4*)&Bs[k][n0];
            acc[0][0] += av.x * bv.x; acc[0][1] += av.x * bv.y; acc[0][2] += av.x * bv.z; acc[0][3] += av.x * bv.w;
            acc[1][0] += av.y * bv.x; acc[1][1] += av.y * bv.y; acc[1][2] += av.y * bv.z; acc[1][3] += av.y * bv.w;
            acc[2][0] += av.z * bv.x; acc[2][1] += av.z * bv.y; acc[2][2] += av.z * bv.z; acc[2][3] += av.z * bv.w;
            acc[3][0] += av.w * bv.x; acc[3][1] += av.w * bv.y; acc[3][2] += av.w * bv.z; acc[3][3] += av.w * bv.w;
        }
        __syncthreads();
    }

    const float4 bv = *(const float4*)(bias + bn * TN + n0);
#pragma unroll
    for (int i = 0; i < 4; i++) {
        float4 v;
        v.x = acc[i][0] + bv.x;
        v.y = acc[i][1] + bv.y;
        v.z = acc[i][2] + bv.z;
        v.w = acc[i][3] + bv.w;
        *(float4*)&C[(size_t)(row0 + m0 + i) * N + bn * TN + n0] = v;
    }
}

// ---------------------------------------------------------------------------
// LSTM recurrence v7: U resident in LDS (residency is architectural — after
// 5 failed attempts at register residency, the allocator always sank/spilled
// the array). 4 blocks/batch (blockIdx = q*64+b; siblings share an XCD under
// round-robin dispatch). Block owns COLS=HN gate columns.
//   F16 path (HN=256): U slice stored as fp16 pairs-over-k (half2 words),
//     COLS*HN/2 words = 128 KB; dot via v_dot2_f32_f16 (exact fp16 products,
//     fp32 accumulate). h also carried as half2 words.
//   F32 path (HN=128): U slice fp32, 64 KB, plain fma.
// Word layout: UW[c][w ^ ((c&7)<<2)] — XOR swizzle keeps b128 reads aligned
// and spreads banks (row length 128 words ≡ 0 mod 32).
// Thread (kq,cp): cols {2cp,2cp+1} x k-range KH. Per step: dot vs LDS U/h,
// NKG-way reduction via LDS, activations, cell update, 4-block h exchange via
// global hbuf + flags (relaxed spin + one acquire fence; parity dbuf).
// ---------------------------------------------------------------------------
typedef _Float16 h2_t __attribute__((ext_vector_type(2)));

__device__ __forceinline__ float fdot2u(unsigned int a, unsigned int b, float c) {
#if __has_builtin(__builtin_amdgcn_fdot2)
    return __builtin_amdgcn_fdot2(__builtin_bit_cast(h2_t, a),
                                  __builtin_bit_cast(h2_t, b), c, false);
#else
    const __half2 ah = __builtin_bit_cast(__half2, a);
    const __half2 bh = __builtin_bit_cast(__half2, b);
    const float2 af = __half22float2(ah), bf = __half22float2(bh);
    return c + af.x * bf.x + af.y * bf.y;
#endif
}
__device__ __forceinline__ unsigned int pack_h2(float x, float y) {
    const __half2 h = __float22half2_rn(make_float2(x, y));
    return __builtin_bit_cast(unsigned int, h);
}
__device__ __forceinline__ float ubits(unsigned int a) { return __builtin_bit_cast(float, a); }

__device__ __forceinline__ float fsig(float z) { return 1.f / (1.f + __expf(-z)); }
__device__ __forceinline__ float ftanh(float z) {
    const float e = __expf(2.f * z);
    return 1.f - 2.f / (e + 1.f);
}

template <int HN, bool F16>
__global__ __launch_bounds__(1024) void lstm_rec_v7(
    const float* __restrict__ xz,   // [B, T, 4*HN]
    const float* __restrict__ U,    // [HN, 4*HN]
    float* __restrict__ hout,       // [B, T, HN] or nullptr
    float* __restrict__ out_last,   // [B, HN] or nullptr
    float* __restrict__ hbuf,       // [2][B_*HN] exchange buffer
    int* __restrict__ flags)        // [B_*4*FSTR], zeroed before launch
{
    constexpr int GATES = 4 * HN;
    constexpr int COLS = HN;            // gate columns per block
    constexpr int CP = COLS / 2;        // column-pairs
    constexpr int NKG = 1024 / CP;      // k-groups
    constexpr int KH = HN / NKG;        // k per thread
    constexpr int HB = HN / 4;          // hidden units per block
    constexpr int KWORDS = F16 ? HN / 2 : HN;   // words per U column / in h
    constexpr int WPT = F16 ? KH / 2 : KH;      // words per col per thread

    __shared__ __align__(16) unsigned int UW[COLS * KWORDS];
    __shared__ __align__(16) unsigned int hW[KWORDS];
    __shared__ __align__(16) float2 zpart[(NKG - 1) * CP];
    __shared__ __align__(16) float act_sh[COLS];

    const int tid = threadIdx.x;
    const int q = blockIdx.x >> 6;      // quarter 0..3
    const int b = blockIdx.x & 63;      // batch element

    const int cp = tid % CP;
    const int kq = tid / CP;            // wave-uniform (CP % 64 == 0)
    const int c0 = 2 * cp;
    const int c1 = c0 + 1;
    const int group = c0 / HB;          // gate 0..3
    const int gcol = group * HN + q * HB + (c0 % HB);
    const int wbase = kq * WPT;
    const int sw0 = (c0 & 7) << 2;
    const int sw1 = (c1 & 7) << 2;

    // ---- one-time: stage U slice into LDS (fp16-packed or fp32 bits) ----
    {
        constexpr int NP = 1024 / COLS;
        const int c = tid % COLS;
        const int part = tid / COLS;
        const int gg = c / HB;
        const int gc = gg * HN + q * HB + (c % HB);
        const int swc = (c & 7) << 2;
        for (int w = part; w < KWORDS; w += NP) {
            unsigned int word;
            if constexpr (F16) {
                const float a = U[(size_t)(2 * w) * GATES + gc];
                const float bb = U[(size_t)(2 * w + 1) * GATES + gc];
                word = pack_h2(a, bb);
            } else {
                word = __builtin_bit_cast(unsigned int, U[(size_t)w * GATES + gc]);
            }
            UW[c * KWORDS + (w ^ swc)] = word;
        }
    }
    if (tid < KWORDS) hW[tid] = 0u;     // h_0 = 0 (fp16 0x0000 / fp32 0.0)
    float cst = 0.f;

    const float* xzb = xz + (size_t)b * T_ * GATES + gcol;
    const int fbase = b * 4;
    const bool tanh_gate = (group == 2);

    float2 z0 = make_float2(0.f, 0.f);
    if (kq == 0) z0 = *(const float2*)xzb;   // step-0 xz
    __syncthreads();

#pragma unroll 1
    for (int t = 0; t < T_; ++t) {
        // ---- dot: z[c0,c1] over this thread's k-range, U and h from LDS ----
        float acc0 = 0.f, acc1 = 0.f;
#pragma unroll
        for (int j = 0; j < WPT; j += 4) {
            const int w = wbase + j;
            const uint4 hw4 = *(const uint4*)&hW[w];                   // wave-uniform bcast
            const uint4 ua = *(const uint4*)&UW[c0 * KWORDS + (w ^ sw0)];
            const uint4 ub = *(const uint4*)&UW[c1 * KWORDS + (w ^ sw1)];
            if constexpr (F16) {
                acc0 = fdot2u(ua.x, hw4.x, acc0);
                acc0 = fdot2u(ua.y, hw4.y, acc0);
                acc0 = fdot2u(ua.z, hw4.z, acc0);
                acc0 = fdot2u(ua.w, hw4.w, acc0);
                acc1 = fdot2u(ub.x, hw4.x, acc1);
                acc1 = fdot2u(ub.y, hw4.y, acc1);
                acc1 = fdot2u(ub.z, hw4.z, acc1);
                acc1 = fdot2u(ub.w, hw4.w, acc1);
            } else {
                acc0 += ubits(ua.x) * ubits(hw4.x); acc1 += ubits(ub.x) * ubits(hw4.x);
                acc0 += ubits(ua.y) * ubits(hw4.y); acc1 += ubits(ub.y) * ubits(hw4.y);
                acc0 += ubits(ua.z) * ubits(hw4.z); acc1 += ubits(ub.z) * ubits(hw4.z);
                acc0 += ubits(ua.w) * ubits(hw4.w); acc1 += ubits(ub.w) * ubits(hw4.w);
            }
        }
        if (kq != 0) zpart[(kq - 1) * CP + cp] = make_float2(acc0, acc1);
        __syncthreads();    // bar1

        // ---- reduce + activations (kq==0 threads) ----
        if (kq == 0) {
            float zx = z0.x + acc0;
            float zy = z0.y + acc1;
#pragma unroll
            for (int r = 0; r < NKG - 1; ++r) {
                const float2 p = zpart[r * CP + cp];
                zx += p.x; zy += p.y;
            }
            if (t + 1 < T_) z0 = *(const float2*)(xzb + (size_t)(t + 1) * GATES);  // prefetch
            float ax, ay;
            if (tanh_gate) { ax = ftanh(zx); ay = ftanh(zy); }
            else           { ax = fsig(zx);  ay = fsig(zy);  }
            *(float2*)&act_sh[c0] = make_float2(ax, ay);
        }
        __syncthreads();    // bar2

        // ---- cell update (wave 0, lanes < HB) ----
        float hnew = 0.f;
        if (tid < HB) {
            const float ig = act_sh[tid];
            const float fg = act_sh[HB + tid];
            const float gg = act_sh[2 * HB + tid];
            const float og = act_sh[3 * HB + tid];
            cst = fg * cst + ig * gg;
            hnew = og * ftanh(cst);
            if (hout) hout[((size_t)b * T_ + t) * HN + q * HB + tid] = hnew;
            if (out_last && t == T_ - 1) out_last[(size_t)b * HN + q * HB + tid] = hnew;
        }

        if (t < T_ - 1) {
            const int s = t & 1;
            // publish own h slice (wave 0 lanes)
            if (tid < HB)
                __hip_atomic_store(&hbuf[(size_t)s * B_ * HN + b * HN + q * HB + tid],
                                   hnew, __ATOMIC_RELAXED, __HIP_MEMORY_SCOPE_AGENT);
            if (tid == 0) {
                __threadfence();   // release: covers wave 0's hbuf stores
                __hip_atomic_store(&flags[(fbase + q) * FSTR], t + 1,
                                   __ATOMIC_RELEASE, __HIP_MEMORY_SCOPE_AGENT);
            }
            // relaxed spin (lanes 0..3), then ONE acquire fence for the wave
            if (tid < 4) {
                while (__hip_atomic_load(&flags[(fbase + tid) * FSTR],
                                         __ATOMIC_RELAXED, __HIP_MEMORY_SCOPE_AGENT) < t + 1) {}
            }
            if (tid < 64) {
                __threadfence();   // acquire: order pull loads after observed flags
                if constexpr (F16) {
                    // 64 lanes x float4 = full 256-float h -> half2 words
                    const float4 hv = *(const float4*)&hbuf[(size_t)s * B_ * HN + b * HN + 4 * tid];
                    unsigned int w0 = pack_h2(hv.x, hv.y);
                    unsigned int w1 = pack_h2(hv.z, hv.w);
                    *(uint2*)&hW[2 * tid] = make_uint2(w0, w1);
                } else {
                    if (tid < HN / 4) {
                        const float4 hv = *(const float4*)&hbuf[(size_t)s * B_ * HN + b * HN + 4 * tid];
                        uint4 wv;
                        wv.x = __builtin_bit_cast(unsigned int, hv.x);
                        wv.y = __builtin_bit_cast(unsigned int, hv.y);
                        wv.z = __builtin_bit_cast(unsigned int, hv.z);
                        wv.w = __builtin_bit_cast(unsigned int, hv.w);
                        *(uint4*)&hW[4 * tid] = wv;
                    }
                }
            }
            __syncthreads();    // bar3
        }
    }
}

// ---------------------------------------------------------------------------
// Launch
// ---------------------------------------------------------------------------
extern "C" void kernel_launch(void* const* d_in, const int* in_sizes, int n_in,
                              void* d_out, int out_size, void* d_ws, size_t ws_size,
                              hipStream_t stream)
{
    const float* x  = (const float*)d_in[0];
    const float* W0 = (const float*)d_in[1];
    const float* U0 = (const float*)d_in[2];
    const float* b0 = (const float*)d_in[3];
    const float* W1 = (const float*)d_in[4];
    const float* U1 = (const float*)d_in[5];
    const float* b1 = (const float*)d_in[6];
    const float* W2 = (const float*)d_in[7];
    const float* U2 = (const float*)d_in[8];
    const float* b2 = (const float*)d_in[9];
    const float* m0 = (const float*)d_in[10];
    const float* m1 = (const float*)d_in[11];
    const float* m2 = (const float*)d_in[12];
    float* out = (float*)d_out;

    // workspace layout (fp32):
    //   xz    : 134217728 B   (64*512*1024 floats, reused by all 3 layers)
    //   h0    :  33554432 B
    //   h1    :  33554432 B
    //   hbuf  :    131072 B   (2 x 64 x 256 floats, shared across layers)
    //   flags :  3 layers x 64*4*FSTR ints = 24576 B
    char* ws = (char*)d_ws;
    float* xz   = (float*)ws;
    float* h0   = (float*)(ws + 134217728);
    float* h1   = (float*)(ws + 134217728 + 33554432);
    float* hbuf = (float*)(ws + 134217728 + 2 * 33554432);
    int*   flg  = (int*)  (ws + 134217728 + 2 * 33554432 + 131072);

    // flags must start at 0 every call (d_ws is poisoned 0xAA)
    hipMemsetAsync(flg, 0, 3 * B_ * 4 * FSTR * sizeof(int), stream);

    const int M = B_ * T_;  // 32768
    const int FL = B_ * 4 * FSTR;

    // Layer 0
    gemm_mask_kernel<<<dim3(1024 / 64, M / 64), 256, 0, stream>>>(x, W0, b0, m0, xz, M, 1024, 128);
    lstm_rec_v7<256, true><<<256, 1024, 0, stream>>>(xz, U0, h0, nullptr, hbuf, flg);

    // Layer 1
    gemm_mask_kernel<<<dim3(1024 / 64, M / 64), 256, 0, stream>>>(h0, W1, b1, m1, xz, M, 1024, 256);
    lstm_rec_v7<256, true><<<256, 1024, 0, stream>>>(xz, U1, h1, nullptr, hbuf, flg + FL);

    // Layer 2 (H=128, fp32 LDS), emit last h only
    gemm_mask_kernel<<<dim3(512 / 64, M / 64), 256, 0, stream>>>(h1, W2, b2, m2, xz, M, 512, 256);
    lstm_rec_v7<128, false><<<256, 1024, 0, stream>>>(xz, U2, nullptr, out, hbuf, flg + 2 * FL);
}